// Round 1
// 2224.220 us; speedup vs baseline: 1.3230x; 1.3230x over previous
//
#include <hip/hip_runtime.h>

// ---------------- constants ----------------
#define TB 4
#define TT 2048
#define DIN 513
#define TOUT 509
#define M2 2036          // TB*TOUT
#define DM 512
#define PR 4096
#define DIc 1024
#define Hh 16
#define CONVD 1152
#define DINP 2192        // 2*DIc + 2*64 + 16
#define ZLD 4384         // 2*DINP (fw|bw stacked)
#define LC 128           // scan chunk length
#define NC 4             // ceil(TOUT/LC)
#define KW1 7182         // true K of patch GEMM
#define KP1 7200         // K padded to mult of 32

typedef __attribute__((ext_vector_type(8))) short s8v;   // 8 bf16 in 4 VGPRs
typedef __attribute__((ext_vector_type(4))) float f4v;   // MFMA accumulator

__device__ __forceinline__ short f2b(float f) {          // fp32 -> bf16 RNE
    unsigned u = __float_as_uint(f);
    u += 0x7fffu + ((u >> 16) & 1u);
    return (short)(u >> 16);
}

// async global->LDS DMA. LDS dest is wave-uniform base + lane*size; global src is per-lane.
__device__ __forceinline__ void gld16(const void* g, void* l) {
    __builtin_amdgcn_global_load_lds(
        (const __attribute__((address_space(1))) unsigned int*)g,
        (__attribute__((address_space(3))) unsigned int*)l, 16, 0, 0);
}
__device__ __forceinline__ void gld4(const void* g, void* l) {
    __builtin_amdgcn_global_load_lds(
        (const __attribute__((address_space(1))) unsigned int*)g,
        (__attribute__((address_space(3))) unsigned int*)l, 4, 0, 0);
}

// ---------------- day-specific input transform (fp32 tiled, bf16 out) ----------------
__global__ __launch_bounds__(256) void day_gemm(const float* __restrict__ x,
                                                const int* __restrict__ day_idx,
                                                const float* __restrict__ day_w,
                                                const float* __restrict__ day_b,
                                                short* __restrict__ hfull) {
    int b = blockIdx.z;
    int day = day_idx[b];
    int n0 = blockIdx.x * 64, m0 = blockIdx.y * 64;
    int tid = threadIdx.x;
    __shared__ float As[16][68], Bs[16][68];
    float acc[4][4] = {};
    int tm = tid >> 4, tn = tid & 15;
    int lrow = tid >> 2, lk = (tid & 3) * 4;
    const float* Ab = x + ((size_t)b * TT + m0) * DIN;
    const float* Bb = day_w + (size_t)day * 512 * 512;
    for (int k0 = 0; k0 < 512; k0 += 16) {
        #pragma unroll
        for (int j = 0; j < 4; j++)
            As[lk + j][lrow] = Ab[(size_t)lrow * DIN + k0 + lk + j];
        int kb = tid >> 4; int nb = (tid & 15) * 4;
        #pragma unroll
        for (int j = 0; j < 4; j++)
            Bs[kb][nb + j] = Bb[(size_t)(k0 + kb) * 512 + n0 + nb + j];
        __syncthreads();
        #pragma unroll
        for (int kk = 0; kk < 16; kk++) {
            float4 av = *(const float4*)&As[kk][tm * 4];
            float4 bv = *(const float4*)&Bs[kk][tn * 4];
            float a[4] = {av.x, av.y, av.z, av.w};
            float bb2[4] = {bv.x, bv.y, bv.z, bv.w};
            #pragma unroll
            for (int i = 0; i < 4; i++)
                #pragma unroll
                for (int j = 0; j < 4; j++) acc[i][j] += a[i] * bb2[j];
        }
        __syncthreads();
    }
    #pragma unroll
    for (int i = 0; i < 4; i++) {
        int m = m0 + tm * 4 + i;
        #pragma unroll
        for (int j = 0; j < 4; j++) {
            int n = n0 + tn * 4 + j;
            float v = acc[i][j] + day_b[day * 512 + n];
            v = v / (1.f + fabsf(v));
            hfull[((size_t)b * TT + m) * DIN + n] = f2b(v);
        }
    }
}

__global__ void copy_xt(const float* __restrict__ x, short* __restrict__ hfull) {
    int idx = blockIdx.x * 256 + threadIdx.x;
    if (idx >= TB * TT) return;
    hfull[(size_t)idx * DIN + 512] = f2b(x[(size_t)idx * DIN + 512]);
}

// ---------------- conversion kernels ----------------
// w1 [4096][7182] fp32 -> [4096][7200] bf16, zero-padded tail (rows only 8B-aligned -> float2)
__global__ void cvt_w1(const float* __restrict__ s, short* __restrict__ d) {
    long idx = (long)blockIdx.x * 256 + threadIdx.x;      // 4096*900 threads, 8 elems each
    if (idx >= (long)4096 * 900) return;
    int row = (int)(idx / 900);
    int kc = (int)(idx % 900) * 8;
    const float* src = s + (long)row * KW1 + kc;
    short* dst = d + (long)row * KP1 + kc;
    if (kc + 8 <= KW1) {
        const float2* s2 = (const float2*)src;
        #pragma unroll
        for (int j = 0; j < 4; j++) {
            float2 u = s2[j];
            dst[2 * j] = f2b(u.x); dst[2 * j + 1] = f2b(u.y);
        }
    } else {
        #pragma unroll
        for (int j = 0; j < 8; j++)
            dst[j] = (kc + j < KW1) ? f2b(src[j]) : (short)0;
    }
}

// generic fp32 -> bf16, n multiple of 4
__global__ void cvtk(const float* __restrict__ s, short* __restrict__ d, long n) {
    long i = ((long)blockIdx.x * 256 + threadIdx.x) * 4;
    if (i >= n) return;
    float4 v = *(const float4*)(s + i);
    d[i] = f2b(v.x); d[i + 1] = f2b(v.y); d[i + 2] = f2b(v.z); d[i + 3] = f2b(v.w);
}

// pack fw|bw out-proj weights: d[n][k], k<1024 from fw[n][k], else bw[n][k-1024]
__global__ void cvt_outw(const float* __restrict__ fw, const float* __restrict__ bw,
                         short* __restrict__ d) {
    long idx = (long)blockIdx.x * 256 + threadIdx.x;      // 512*2048/4
    if (idx >= (long)512 * 512) return;
    long e = idx * 4;
    int n = (int)(e >> 11);
    int k = (int)(e & 2047);
    const float* src = (k < 1024) ? (fw + (long)n * 1024 + k)
                                  : (bw + (long)n * 1024 + (k - 1024));
    float4 v = *(const float4*)src;
    short* dst = d + e;
    dst[0] = f2b(v.x); dst[1] = f2b(v.y); dst[2] = f2b(v.z); dst[3] = f2b(v.w);
}

// ---------------- bf16 MFMA GEMM, global_load_lds staging (m97 structure) ----------------
// A: bf16, row m at (m/rowDiv)*sOuter + (m%rowDiv)*sInner (element units), K contiguous.
// Bw: bf16 [N][K]. K must be a multiple of 32.
// AW=16: A rows 16B-aligned (2x gld16/wave). AW=4: only 4B-aligned (8x gld4/wave).
template <int ACT, int ACCUM, int OUTBF, int AW>
__global__ __launch_bounds__(256) void bgemm(const short* __restrict__ A,
                                             const short* __restrict__ Bw,
                                             const float* __restrict__ bias,
                                             void* __restrict__ Cout,
                                             int M, int N, int K,
                                             int rowDiv, long sOuter, long sInner, int ldc) {
    __shared__ short As[128 * 32];
    __shared__ short Bs[128 * 32];
    int m0 = blockIdx.y * 128, n0 = blockIdx.x * 128;
    int tid = threadIdx.x;
    int wave = tid >> 6, lane = tid & 63;
    int wm = (wave & 1) * 64, wn = (wave >> 1) * 64;
    int lm = lane & 15, quad = lane >> 4;

    const short* Ap[(AW == 4) ? 8 : 2];
    if constexpr (AW == 4) {
        int kcc = (lane & 15) * 2;                        // 4B chunk within 32-col row
        #pragma unroll
        for (int c = 0; c < 8; c++) {
            int r = m0 + wave * 32 + c * 4 + (lane >> 4);
            r = min(r, M - 1);
            Ap[c] = A + (long)(r / rowDiv) * sOuter + (long)(r % rowDiv) * sInner + kcc;
        }
    } else {
        int kca = (lane & 3) * 8;                         // 16B chunk within 32-col row
        int r0 = min(m0 + wave * 32 + (lane >> 2), M - 1);
        int r1 = min(m0 + wave * 32 + 16 + (lane >> 2), M - 1);
        Ap[0] = A + (long)(r0 / rowDiv) * sOuter + (long)(r0 % rowDiv) * sInner + kca;
        Ap[1] = A + (long)(r1 / rowDiv) * sOuter + (long)(r1 % rowDiv) * sInner + kca;
    }
    int kcb = (lane & 3) * 8;
    int b0 = min(n0 + wave * 32 + (lane >> 2), N - 1);
    int b1 = min(n0 + wave * 32 + 16 + (lane >> 2), N - 1);
    const short* Bp0 = Bw + (long)b0 * K + kcb;
    const short* Bp1 = Bw + (long)b1 * K + kcb;
    short* lA = As + wave * 1024;                         // rows [wave*32, wave*32+32)
    short* lB = Bs + wave * 1024;

    f4v acc[4][4];
    #pragma unroll
    for (int i = 0; i < 4; i++)
        #pragma unroll
        for (int j = 0; j < 4; j++) acc[i][j] = (f4v){0.f, 0.f, 0.f, 0.f};

    for (int k0 = 0; k0 < K; k0 += 32) {
        if constexpr (AW == 4) {
            #pragma unroll
            for (int c = 0; c < 8; c++)
                gld4(Ap[c] + k0, lA + c * 128);
        } else {
            gld16(Ap[0] + k0, lA);
            gld16(Ap[1] + k0, lA + 512);
        }
        gld16(Bp0 + k0, lB);
        gld16(Bp1 + k0, lB + 512);
        __syncthreads();                                  // waits vmcnt(0): tiles landed
        s8v af[4], bf[4];
        #pragma unroll
        for (int i = 0; i < 4; i++)
            af[i] = *(const s8v*)&As[(wm + i * 16 + lm) * 32 + quad * 8];
        #pragma unroll
        for (int j = 0; j < 4; j++)
            bf[j] = *(const s8v*)&Bs[(wn + j * 16 + lm) * 32 + quad * 8];
        #pragma unroll
        for (int i = 0; i < 4; i++)
            #pragma unroll
            for (int j = 0; j < 4; j++)
                acc[i][j] = __builtin_amdgcn_mfma_f32_16x16x32_bf16(af[i], bf[j], acc[i][j], 0, 0, 0);
        __syncthreads();                                  // all reads done before restage
    }

    #pragma unroll
    for (int i = 0; i < 4; i++) {
        #pragma unroll
        for (int e = 0; e < 4; e++) {
            int m = m0 + wm + i * 16 + quad * 4 + e;
            if (m >= M) continue;
            #pragma unroll
            for (int j = 0; j < 4; j++) {
                int n = n0 + wn + j * 16 + lm;
                if (n >= N) continue;
                float v = acc[i][j][e];
                if (bias) v += bias[n];
                if (ACT == 1) v = v / (1.f + fabsf(v));
                long ci = (long)m * ldc + n;
                if constexpr (OUTBF) {
                    ((short*)Cout)[ci] = f2b(v);
                } else {
                    float* Cf = (float*)Cout;
                    if constexpr (ACCUM) v += Cf[ci];
                    Cf[ci] = v;
                }
            }
        }
    }
}

// ---------------- LayerNorm (bf16 out) ----------------
__global__ __launch_bounds__(64) void ln_kernel(const float* __restrict__ h,
                                                const float* __restrict__ w,
                                                const float* __restrict__ bgain,
                                                short* __restrict__ hn) {
    int m = blockIdx.x, lane = threadIdx.x;
    const float* row = h + (size_t)m * DM;
    float v[8]; float s = 0.f;
    #pragma unroll
    for (int j = 0; j < 8; j++) { v[j] = row[lane + j * 64]; s += v[j]; }
    for (int o = 1; o < 64; o <<= 1) s += __shfl_xor(s, o);
    float mu = s * (1.f / DM);
    float var = 0.f;
    #pragma unroll
    for (int j = 0; j < 8; j++) { float d = v[j] - mu; var += d * d; }
    for (int o = 1; o < 64; o <<= 1) var += __shfl_xor(var, o);
    float inv = rsqrtf(var * (1.f / DM) + 1e-5f);
    #pragma unroll
    for (int j = 0; j < 8; j++) {
        int c = lane + j * 64;
        hn[(size_t)m * DM + c] = f2b((v[j] - mu) * inv * w[c] + bgain[c]);
    }
}

// ---------------- depthwise conv (dir-aware) + SiLU ----------------
__global__ void conv_kernel(const float* __restrict__ zx2,
                            const float* __restrict__ cw,
                            const float* __restrict__ cb,
                            float* __restrict__ xbcc) {
    int idx = blockIdx.x * 256 + threadIdx.x;
    if (idx >= 2 * M2 * CONVD) return;
    int dir = idx / (M2 * CONVD);
    int r = idx - dir * (M2 * CONVD);
    int m = r / CONVD; int c = r - m * CONVD;
    int b = m / TOUT; int t = m - b * TOUT;
    float acc = cb[dir * CONVD + c];
    const float* w = cw + (size_t)(dir * CONVD + c) * 4;
    #pragma unroll
    for (int k = 0; k < 4; k++) {
        int tp = dir ? (t + 3 - k) : (t - 3 + k);
        if (tp >= 0 && tp < TOUT)
            acc += w[k] * zx2[(size_t)(b * TOUT + tp) * ZLD + dir * DINP + DIc + c];
    }
    xbcc[(size_t)idx] = acc / (1.f + expf(-acc));   // silu
}

// ---------------- dt softplus + dA ----------------
__global__ void dt_kernel(const float* __restrict__ zx2,
                          const float* __restrict__ dtB,
                          const float* __restrict__ alog,
                          float* __restrict__ dtb, float* __restrict__ dab) {
    int idx = blockIdx.x * 256 + threadIdx.x;
    if (idx >= 2 * M2 * Hh) return;
    int dir = idx / (M2 * Hh);
    int r = idx - dir * (M2 * Hh);
    int m = r / Hh; int hh = r - m * Hh;
    float raw = zx2[(size_t)m * ZLD + dir * DINP + DIc + CONVD + hh] + dtB[dir * Hh + hh];
    float sp = raw > 20.f ? raw : log1pf(expf(raw));
    float A = -expf(alog[dir * Hh + hh]);
    dtb[idx] = sp;
    dab[idx] = expf(sp * A);
}

// ---------------- chunked selective scan ----------------
__global__ __launch_bounds__(64) void scan_local(const float* __restrict__ xbcc,
                                                 const float* __restrict__ dtb,
                                                 const float* __restrict__ dab,
                                                 const float* __restrict__ Dp_pair,
                                                 float* __restrict__ ybuf,
                                                 float* __restrict__ Hbuf,
                                                 float* __restrict__ Pcum) {
    int h = blockIdx.x & 15, chunk = blockIdx.x >> 4;
    int b = blockIdx.y, dir = blockIdx.z;
    int lane = threadIdx.x;                 // lane = p (headdim)
    int s0 = chunk * LC;
    int s1 = min(s0 + LC, TOUT);
    __shared__ __align__(16) float bsh[2][64];
    __shared__ __align__(16) float csh[2][64];
    float st[64];
    #pragma unroll
    for (int n = 0; n < 64; n++) st[n] = 0.f;
    float Dpv = Dp_pair[dir * Hh + h];
    const float* xb = xbcc + (size_t)dir * M2 * CONVD;
    long dtbase = (size_t)(dir * M2 + b * TOUT) * Hh + h;
    int id = (dir * TB + b) * Hh + h;
    float* pcm = Pcum + (size_t)id * TOUT;

    int tt0 = dir ? (TOUT - 1 - s0) : s0;
    const float* row0 = xb + (size_t)(b * TOUT + tt0) * CONVD;
    float bcur = row0[DIc + lane];
    float ccur = row0[DIc + 64 + lane];
    float xcur = row0[h * 64 + lane];
    float dtcur = dtb[dtbase + (long)tt0 * Hh];
    float dacur = dab[dtbase + (long)tt0 * Hh];
    float P = 1.f;

    for (int s = s0; s < s1; s++) {
        int pb = s & 1;
        bsh[pb][lane] = bcur;
        csh[pb][lane] = ccur;
        float xp = xcur, dtt = dtcur, da = dacur;
        __syncthreads();
        if (s + 1 < s1) {
            int tn = dir ? (TOUT - 1 - (s + 1)) : (s + 1);
            const float* rown = xb + (size_t)(b * TOUT + tn) * CONVD;
            bcur = rown[DIc + lane];
            ccur = rown[DIc + 64 + lane];
            xcur = rown[h * 64 + lane];
            dtcur = dtb[dtbase + (long)tn * Hh];
            dacur = dab[dtbase + (long)tn * Hh];
        }
        float common = dtt * xp;
        float y0 = 0.f, y1 = 0.f, y2 = 0.f, y3 = 0.f;
        #pragma unroll
        for (int n4 = 0; n4 < 16; n4++) {
            float4 bv = ((const float4*)bsh[pb])[n4];
            float4 cv = ((const float4*)csh[pb])[n4];
            int n = n4 * 4;
            st[n]     = st[n]     * da + common * bv.x; y0 += st[n]     * cv.x;
            st[n + 1] = st[n + 1] * da + common * bv.y; y1 += st[n + 1] * cv.y;
            st[n + 2] = st[n + 2] * da + common * bv.z; y2 += st[n + 2] * cv.z;
            st[n + 3] = st[n + 3] * da + common * bv.w; y3 += st[n + 3] * cv.w;
        }
        int tt = dir ? (TOUT - 1 - s) : s;
        int m = b * TOUT + tt;
        ybuf[((size_t)dir * M2 + m) * DIc + h * 64 + lane] = (y0 + y1) + (y2 + y3) + Dpv * xp;
        P *= da;
        if (lane == 0) pcm[s] = P;
    }
    float* Ho = Hbuf + (((size_t)id * NC + chunk) * 64 + lane) * 64;
    #pragma unroll
    for (int n4 = 0; n4 < 16; n4++) {
        ((float4*)Ho)[n4] = (float4){st[n4 * 4], st[n4 * 4 + 1], st[n4 * 4 + 2], st[n4 * 4 + 3]};
    }
}

__global__ __launch_bounds__(64) void scan_combine(float* __restrict__ Hbuf,
                                                   const float* __restrict__ Pcum) {
    int id = blockIdx.x;
    int lane = threadIdx.x;
    float Hin[64];
    #pragma unroll
    for (int n = 0; n < 64; n++) Hin[n] = 0.f;
    const float* pcm = Pcum + (size_t)id * TOUT;
    for (int c = 0; c < NC; c++) {
        float* Hp = Hbuf + (((size_t)id * NC + c) * 64 + lane) * 64;
        float Hout[64];
        #pragma unroll
        for (int n4 = 0; n4 < 16; n4++) {
            float4 v = ((const float4*)Hp)[n4];
            Hout[n4 * 4] = v.x; Hout[n4 * 4 + 1] = v.y;
            Hout[n4 * 4 + 2] = v.z; Hout[n4 * 4 + 3] = v.w;
        }
        #pragma unroll
        for (int n4 = 0; n4 < 16; n4++)
            ((float4*)Hp)[n4] = (float4){Hin[n4 * 4], Hin[n4 * 4 + 1], Hin[n4 * 4 + 2], Hin[n4 * 4 + 3]};
        int send = min((c + 1) * LC, TOUT) - 1;
        float Pe = pcm[send];
        #pragma unroll
        for (int n = 0; n < 64; n++) Hin[n] = Hout[n] + Pe * Hin[n];
    }
}

__global__ __launch_bounds__(64) void scan_fix(const float* __restrict__ xbcc,
                                               const float* __restrict__ Hbuf,
                                               const float* __restrict__ Pcum,
                                               float* __restrict__ ybuf) {
    int h = blockIdx.x & 15;
    int q = (blockIdx.x >> 4) & 3;
    int c = 1 + (blockIdx.x >> 6);
    int b = blockIdx.y, dir = blockIdx.z, lane = threadIdx.x;
    int s0 = c * LC;
    int s1 = min(s0 + LC, TOUT);
    int sa = s0 + q * (LC / 4);
    int se = min(sa + LC / 4, s1);
    if (sa >= se) return;
    int id = (dir * TB + b) * Hh + h;
    float Hr[64];
    const float* Hp = Hbuf + (((size_t)id * NC + c) * 64 + lane) * 64;
    #pragma unroll
    for (int n4 = 0; n4 < 16; n4++) {
        float4 v = ((const float4*)Hp)[n4];
        Hr[n4 * 4] = v.x; Hr[n4 * 4 + 1] = v.y; Hr[n4 * 4 + 2] = v.z; Hr[n4 * 4 + 3] = v.w;
    }
    const float* pcm = Pcum + (size_t)id * TOUT;
    const float* xb = xbcc + (size_t)dir * M2 * CONVD;
    for (int s = sa; s < se; s++) {
        int tt = dir ? (TOUT - 1 - s) : s;
        const float4* crow = (const float4*)(xb + (size_t)(b * TOUT + tt) * CONVD + DIc + 64);
        float acc = 0.f;
        #pragma unroll
        for (int n4 = 0; n4 < 16; n4++) {
            float4 cv = crow[n4];
            acc += Hr[n4 * 4] * cv.x + Hr[n4 * 4 + 1] * cv.y
                 + Hr[n4 * 4 + 2] * cv.z + Hr[n4 * 4 + 3] * cv.w;
        }
        size_t yi = ((size_t)dir * M2 + b * TOUT + tt) * DIc + h * 64 + lane;
        ybuf[yi] += pcm[s] * acc;
    }
}

// ---------------- gate (silu(z)) + RMSNorm -> bf16 fw|bw interleaved rows ----------------
__global__ __launch_bounds__(64) void grms_kernel(const float* __restrict__ ybuf,
                                                  const float* __restrict__ zx2,
                                                  const float* __restrict__ nw,
                                                  short* __restrict__ yo) {
    int m = blockIdx.x, dir = blockIdx.y, lane = threadIdx.x;
    const float* y = ybuf + ((size_t)dir * M2 + m) * DIc;
    const float* z = zx2 + (size_t)m * ZLD + dir * DINP;
    float g[16]; float ss = 0.f;
    #pragma unroll
    for (int j = 0; j < 16; j++) {
        int c = lane + j * 64;
        float zv = z[c];
        float gv = y[c] * (zv / (1.f + expf(-zv)));
        g[j] = gv; ss += gv * gv;
    }
    for (int o = 1; o < 64; o <<= 1) ss += __shfl_xor(ss, o);
    float sc = rsqrtf(ss * (1.f / DIc) + 1e-5f);
    #pragma unroll
    for (int j = 0; j < 16; j++) {
        int c = lane + j * 64;
        yo[(size_t)m * (2 * DIc) + dir * DIc + c] = f2b(g[j] * sc * nw[dir * DIc + c]);
    }
}

// ---------------- final classifier head (fp32 output) ----------------
__global__ __launch_bounds__(64) void outk(const float* __restrict__ h,
                                           const float* __restrict__ ow,
                                           const float* __restrict__ ob,
                                           float* __restrict__ out) {
    int m = blockIdx.x, lane = threadIdx.x;
    __shared__ float hs[DM];
    #pragma unroll
    for (int j = 0; j < 8; j++) hs[lane + j * 64] = h[(size_t)m * DM + lane + j * 64];
    __syncthreads();
    if (lane < 41) {
        float acc = ob[lane];
        for (int d = 0; d < DM; d++) acc += hs[d] * ow[lane * DM + d];
        out[(size_t)m * 41 + lane] = acc;
    }
}

// ---------------- launch ----------------
extern "C" void kernel_launch(void* const* d_in, const int* in_sizes, int n_in,
                              void* d_out, int out_size, void* d_ws, size_t ws_size,
                              hipStream_t stream) {
    const float* x        = (const float*)d_in[0];
    const int*   day_idx  = (const int*)d_in[1];
    const float* day_w    = (const float*)d_in[2];
    const float* day_b    = (const float*)d_in[3];
    const float* w1       = (const float*)d_in[4];
    const float* b1       = (const float*)d_in[5];
    const float* w2       = (const float*)d_in[6];
    const float* b2       = (const float*)d_in[7];
    const float* ln_w     = (const float*)d_in[8];
    const float* ln_b     = (const float*)d_in[9];
    const float* m_in_w   = (const float*)d_in[10];
    const float* m_conv_w = (const float*)d_in[11];
    const float* m_conv_b = (const float*)d_in[12];
    const float* m_dt     = (const float*)d_in[13];
    const float* m_Alog   = (const float*)d_in[14];
    const float* m_D      = (const float*)d_in[15];
    const float* m_norm_w = (const float*)d_in[16];
    const float* m_out_w  = (const float*)d_in[17];
    const float* out_w    = (const float*)d_in[18];
    const float* out_b    = (const float*)d_in[19];

    float* ws = (float*)d_ws;
    // ---- loop-phase overlay (region U) ----
    float* zx2  = ws;                          // [2036][4384]           = 8,925,824 f
    float* xbcc = ws + 8925824;                // [2][2036][1152]        = 4,690,944 f
    short* ybf  = (short*)(ws + 8925824);      // [2036][2048] bf16 (overlays dead xbcc)
    float* ybuf = ws + 13616768;               // [2][2036][1024]        = 4,169,728 f
    float* Hbuf = ws + 17786496;               // [128][NC][64][64]      = 2,097,152 f
    float* Pcum = ws + 19883648;               // [128][509]             = 65,152 f
    float* dtb  = ws + 19948800;               // 65,152 f
    float* dab  = ws + 20013952;               // 65,152 f
    short* inwb = (short*)(ws + 20079104);     // [4384][512] bf16       = 1,122,304 f
    short* outwb= (short*)(ws + 21201408);     // [512][2048] bf16       = 524,288 f
    // ---- prologue-phase overlay (same region U, earlier lifetimes) ----
    short* hfb  = (short*)ws;                  // [4][2048][513] bf16    = 2,103,296 f
    short* B1   = (short*)(ws + 2103296);      // [4096][7200] bf16      = 14,745,600 f
    short* h1b  = (short*)(ws + 16848896);     // [2036][4096] bf16      = 4,169,728 f
    short* w2b  = (short*)(ws + 21018624);     // [512][4096] bf16       = 1,048,576 f
    // ---- persistent ----
    float* hbuf = ws + 22067200;               // [2036][512]            = 1,042,432 f
    short* hnb  = (short*)(ws + 23109632);     // [2036][512] bf16       = 521,216 f
    // end = 23,630,848 floats (<= previous 23,687,040)

    day_gemm<<<dim3(8, 32, 4), 256, 0, stream>>>(x, day_idx, day_w, day_b, hfb);
    copy_xt<<<32, 256, 0, stream>>>(x, hfb);
    cvt_w1<<<14400, 256, 0, stream>>>(w1, B1);
    cvtk<<<2048, 256, 0, stream>>>(w2, w2b, (long)512 * PR);
    // patch-projection GEMM: A rows are the bf16 hfull patch windows (contiguous, 8B-aligned -> AW=4)
    bgemm<1, 0, 1, 4><<<dim3(32, 16), 256, 0, stream>>>(hfb, B1, b1, h1b,
                                                        M2, PR, KP1, TOUT, (long)TT * DIN, (long)4 * DIN, PR);
    bgemm<0, 0, 0, 16><<<dim3(4, 16), 256, 0, stream>>>(h1b, w2b, b2, hbuf,
                                                        M2, DM, PR, 1, (long)PR, 0L, DM);
    for (int i = 0; i < 5; i++) {
        ln_kernel<<<M2, 64, 0, stream>>>(hbuf, ln_w + i * DM, ln_b + i * DM, hnb);
        cvtk<<<2192, 256, 0, stream>>>(m_in_w + (size_t)2 * i * DINP * DM, inwb, (long)2 * DINP * DM);
        bgemm<0, 0, 0, 16><<<dim3(35, 16), 256, 0, stream>>>(hnb, inwb, nullptr, zx2,
                                                             M2, ZLD, DM, 1, (long)DM, 0L, ZLD);
        conv_kernel<<<(2 * M2 * CONVD + 255) / 256, 256, 0, stream>>>(
            zx2, m_conv_w + (size_t)2 * i * CONVD * 4, m_conv_b + (size_t)2 * i * CONVD, xbcc);
        dt_kernel<<<(2 * M2 * Hh + 255) / 256, 256, 0, stream>>>(
            zx2, m_dt + 2 * i * Hh, m_Alog + 2 * i * Hh, dtb, dab);
        scan_local<<<dim3(Hh * NC, TB, 2), 64, 0, stream>>>(xbcc, dtb, dab, m_D + 2 * i * Hh,
                                                            ybuf, Hbuf, Pcum);
        scan_combine<<<128, 64, 0, stream>>>(Hbuf, Pcum);
        scan_fix<<<dim3(Hh * 4 * (NC - 1), TB, 2), 64, 0, stream>>>(xbcc, Hbuf, Pcum, ybuf);
        grms_kernel<<<dim3(M2, 2), 64, 0, stream>>>(ybuf, zx2, m_norm_w + (size_t)2 * i * DIc, ybf);
        cvt_outw<<<1024, 256, 0, stream>>>(m_out_w + (size_t)(2 * i) * DM * DIc,
                                           m_out_w + (size_t)(2 * i + 1) * DM * DIc, outwb);
        // merged fw+bw out-projection: K = 2048
        bgemm<0, 1, 0, 16><<<dim3(4, 16), 256, 0, stream>>>(ybf, outwb, nullptr, hbuf,
                                                            M2, DM, 2 * DIc, 1, (long)(2 * DIc), 0L, DM);
    }
    outk<<<M2, 64, 0, stream>>>(hbuf, out_w, out_b, (float*)d_out);
}

// Round 2
// 2179.873 us; speedup vs baseline: 1.3499x; 1.0203x over previous
//
#include <hip/hip_runtime.h>

// ---------------- constants ----------------
#define TB 4
#define TT 2048
#define DIN 513
#define TOUT 509
#define M2 2036          // TB*TOUT
#define DM 512
#define PR 4096
#define DIc 1024
#define Hh 16
#define CONVD 1152
#define DINP 2192        // 2*DIc + 2*64 + 16
#define ZLD 4384         // 2*DINP (fw|bw stacked)
#define LC 128           // scan chunk length
#define NC 4             // ceil(TOUT/LC)
#define KW1 7182         // true K of patch GEMM
#define KP1 7200         // K padded to mult of 32

typedef __attribute__((ext_vector_type(8))) short s8v;   // 8 bf16 in 4 VGPRs
typedef __attribute__((ext_vector_type(4))) float f4v;   // MFMA accumulator

__device__ __forceinline__ short f2b(float f) {          // fp32 -> bf16 RNE
    unsigned u = __float_as_uint(f);
    u += 0x7fffu + ((u >> 16) & 1u);
    return (short)(u >> 16);
}

// async global->LDS DMA. LDS dest is wave-uniform base + lane*size; global src is per-lane.
__device__ __forceinline__ void gld16(const void* g, void* l) {
    __builtin_amdgcn_global_load_lds(
        (const __attribute__((address_space(1))) unsigned int*)g,
        (__attribute__((address_space(3))) unsigned int*)l, 16, 0, 0);
}

// ---------------- day-specific input transform (fp32 tiled, bf16 out) ----------------
__global__ __launch_bounds__(256) void day_gemm(const float* __restrict__ x,
                                                const int* __restrict__ day_idx,
                                                const float* __restrict__ day_w,
                                                const float* __restrict__ day_b,
                                                short* __restrict__ hfull) {
    int b = blockIdx.z;
    int day = day_idx[b];
    int n0 = blockIdx.x * 64, m0 = blockIdx.y * 64;
    int tid = threadIdx.x;
    __shared__ float As[16][68], Bs[16][68];
    float acc[4][4] = {};
    int tm = tid >> 4, tn = tid & 15;
    int lrow = tid >> 2, lk = (tid & 3) * 4;
    const float* Ab = x + ((size_t)b * TT + m0) * DIN;
    const float* Bb = day_w + (size_t)day * 512 * 512;
    for (int k0 = 0; k0 < 512; k0 += 16) {
        #pragma unroll
        for (int j = 0; j < 4; j++)
            As[lk + j][lrow] = Ab[(size_t)lrow * DIN + k0 + lk + j];
        int kb = tid >> 4; int nb = (tid & 15) * 4;
        #pragma unroll
        for (int j = 0; j < 4; j++)
            Bs[kb][nb + j] = Bb[(size_t)(k0 + kb) * 512 + n0 + nb + j];
        __syncthreads();
        #pragma unroll
        for (int kk = 0; kk < 16; kk++) {
            float4 av = *(const float4*)&As[kk][tm * 4];
            float4 bv = *(const float4*)&Bs[kk][tn * 4];
            float a[4] = {av.x, av.y, av.z, av.w};
            float bb2[4] = {bv.x, bv.y, bv.z, bv.w};
            #pragma unroll
            for (int i = 0; i < 4; i++)
                #pragma unroll
                for (int j = 0; j < 4; j++) acc[i][j] += a[i] * bb2[j];
        }
        __syncthreads();
    }
    #pragma unroll
    for (int i = 0; i < 4; i++) {
        int m = m0 + tm * 4 + i;
        #pragma unroll
        for (int j = 0; j < 4; j++) {
            int n = n0 + tn * 4 + j;
            float v = acc[i][j] + day_b[day * 512 + n];
            v = v / (1.f + fabsf(v));
            hfull[((size_t)b * TT + m) * DIN + n] = f2b(v);
        }
    }
}

__global__ void copy_xt(const float* __restrict__ x, short* __restrict__ hfull) {
    int idx = blockIdx.x * 256 + threadIdx.x;
    if (idx >= TB * TT) return;
    hfull[(size_t)idx * DIN + 512] = f2b(x[(size_t)idx * DIN + 512]);
}

// ---------------- patch expansion: hfull window (contiguous) -> padded 16B-aligned rows ----------------
__global__ __launch_bounds__(256) void expand_patches(const short* __restrict__ hfb,
                                                      short* __restrict__ Apad) {
    int m = blockIdx.x;                       // 0..M2
    int b = m / TOUT, t0 = m - b * TOUT;
    const short* src = hfb + ((size_t)b * TT + (size_t)t0 * 4) * DIN;  // 14 rows contiguous = 7182 shorts
    short* dst = Apad + (size_t)m * KP1;
    int tid = threadIdx.x;
    for (int k = tid; k < KW1; k += 256) dst[k] = src[k];
    if (tid < KP1 - KW1) dst[KW1 + tid] = 0;
}

// ---------------- conversion kernels ----------------
// w1 rows [r0, r0+rows) fp32 [.][7182] -> bf16 [.][7200], zero-padded tail
__global__ void cvt_w1(const float* __restrict__ s, short* __restrict__ d, int rows) {
    long idx = (long)blockIdx.x * 256 + threadIdx.x;
    if (idx >= (long)rows * 900) return;
    int row = (int)(idx / 900);
    int kc = (int)(idx % 900) * 8;
    const float* src = s + (long)row * KW1 + kc;
    short* dst = d + (long)row * KP1 + kc;
    if (kc + 8 <= KW1) {
        const float2* s2 = (const float2*)src;
        #pragma unroll
        for (int j = 0; j < 4; j++) {
            float2 u = s2[j];
            dst[2 * j] = f2b(u.x); dst[2 * j + 1] = f2b(u.y);
        }
    } else {
        #pragma unroll
        for (int j = 0; j < 8; j++)
            dst[j] = (kc + j < KW1) ? f2b(src[j]) : (short)0;
    }
}

// generic fp32 -> bf16, n multiple of 4
__global__ void cvtk(const float* __restrict__ s, short* __restrict__ d, long n) {
    long i = ((long)blockIdx.x * 256 + threadIdx.x) * 4;
    if (i >= n) return;
    float4 v = *(const float4*)(s + i);
    d[i] = f2b(v.x); d[i + 1] = f2b(v.y); d[i + 2] = f2b(v.z); d[i + 3] = f2b(v.w);
}

// pack fw|bw out-proj weights: d[n][k], k<1024 from fw[n][k], else bw[n][k-1024]
__global__ void cvt_outw(const float* __restrict__ fw, const float* __restrict__ bw,
                         short* __restrict__ d) {
    long idx = (long)blockIdx.x * 256 + threadIdx.x;      // 512*2048/4
    if (idx >= (long)512 * 512) return;
    long e = idx * 4;
    int n = (int)(e >> 11);
    int k = (int)(e & 2047);
    const float* src = (k < 1024) ? (fw + (long)n * 1024 + k)
                                  : (bw + (long)n * 1024 + (k - 1024));
    float4 v = *(const float4*)src;
    short* dst = d + e;
    dst[0] = f2b(v.x); dst[1] = f2b(v.y); dst[2] = f2b(v.z); dst[3] = f2b(v.w);
}

// fill C with broadcast bias (pre-pass for atomic split-K)
__global__ void fillb(float* __restrict__ dst, const float* __restrict__ b, int total, int N) {
    int idx = blockIdx.x * 256 + threadIdx.x;
    if (idx >= total) return;
    dst[idx] = b[idx & (N - 1)];
}

// ---------------- bf16 MFMA GEMM, global_load_lds staging (m97 structure) ----------------
// A: bf16, row m at (m/rowDiv)*sOuter + (m%rowDiv)*sInner (element units), K contiguous,
// rows 16B-aligned. Bw: bf16 [N][K]. K multiple of 32.
// ATOMIC=1: split-K over gridDim.z, partial sums via unsafeAtomicAdd (bias must be null, ACT=0).
template <int ACT, int ACCUM, int OUTBF, int ATOMIC>
__global__ __launch_bounds__(256) void bgemm(const short* __restrict__ A,
                                             const short* __restrict__ Bw,
                                             const float* __restrict__ bias,
                                             void* __restrict__ Cout,
                                             int M, int N, int K,
                                             int rowDiv, long sOuter, long sInner, int ldc) {
    __shared__ short As[128 * 32];
    __shared__ short Bs[128 * 32];
    // bijective XCD-aware swizzle (m204): per-XCD contiguous chunks of the grid
    int nwg = gridDim.x * gridDim.y;
    int orig = blockIdx.y * gridDim.x + blockIdx.x;
    int q = nwg >> 3, rr = nwg & 7;
    int xcd = orig & 7, ii = orig >> 3;
    int wg = (xcd < rr ? xcd * (q + 1) : rr * (q + 1) + (xcd - rr) * q) + ii;
    int bx = wg % gridDim.x, by = wg / gridDim.x;
    int m0 = by * 128, n0 = bx * 128;

    int tid = threadIdx.x;
    int wave = tid >> 6, lane = tid & 63;
    int wm = (wave & 1) * 64, wn = (wave >> 1) * 64;
    int lm = lane & 15, quad = lane >> 4;

    int kca = (lane & 3) * 8;                         // 16B chunk within 32-col row
    int r0 = min(m0 + wave * 32 + (lane >> 2), M - 1);
    int r1 = min(m0 + wave * 32 + 16 + (lane >> 2), M - 1);
    const short* Ap0 = A + (long)(r0 / rowDiv) * sOuter + (long)(r0 % rowDiv) * sInner + kca;
    const short* Ap1 = A + (long)(r1 / rowDiv) * sOuter + (long)(r1 % rowDiv) * sInner + kca;
    int b0 = min(n0 + wave * 32 + (lane >> 2), N - 1);
    int b1 = min(n0 + wave * 32 + 16 + (lane >> 2), N - 1);
    const short* Bp0 = Bw + (long)b0 * K + kca;
    const short* Bp1 = Bw + (long)b1 * K + kca;
    short* lA = As + wave * 1024;                     // rows [wave*32, wave*32+32)
    short* lB = Bs + wave * 1024;

    f4v acc[4][4];
    #pragma unroll
    for (int i = 0; i < 4; i++)
        #pragma unroll
        for (int j = 0; j < 4; j++) acc[i][j] = (f4v){0.f, 0.f, 0.f, 0.f};

    int kper = K, kbeg = 0;
    if constexpr (ATOMIC) { kper = K / (int)gridDim.z; kbeg = blockIdx.z * kper; }
    for (int k0 = kbeg; k0 < kbeg + kper; k0 += 32) {
        gld16(Ap0 + k0, lA);
        gld16(Ap1 + k0, lA + 512);
        gld16(Bp0 + k0, lB);
        gld16(Bp1 + k0, lB + 512);
        __syncthreads();                              // waits vmcnt(0): tiles landed
        s8v af[4], bf[4];
        #pragma unroll
        for (int i = 0; i < 4; i++)
            af[i] = *(const s8v*)&As[(wm + i * 16 + lm) * 32 + quad * 8];
        #pragma unroll
        for (int j = 0; j < 4; j++)
            bf[j] = *(const s8v*)&Bs[(wn + j * 16 + lm) * 32 + quad * 8];
        #pragma unroll
        for (int i = 0; i < 4; i++)
            #pragma unroll
            for (int j = 0; j < 4; j++)
                acc[i][j] = __builtin_amdgcn_mfma_f32_16x16x32_bf16(af[i], bf[j], acc[i][j], 0, 0, 0);
        __syncthreads();                              // all reads done before restage
    }

    #pragma unroll
    for (int i = 0; i < 4; i++) {
        #pragma unroll
        for (int e = 0; e < 4; e++) {
            int m = m0 + wm + i * 16 + quad * 4 + e;
            if (m >= M) continue;
            #pragma unroll
            for (int j = 0; j < 4; j++) {
                int n = n0 + wn + j * 16 + lm;
                if (n >= N) continue;
                float v = acc[i][j][e];
                if (bias) v += bias[n];
                if (ACT == 1) v = v / (1.f + fabsf(v));
                long ci = (long)m * ldc + n;
                if constexpr (OUTBF) {
                    ((short*)Cout)[ci] = f2b(v);
                } else if constexpr (ATOMIC) {
                    unsafeAtomicAdd(&((float*)Cout)[ci], v);
                } else {
                    float* Cf = (float*)Cout;
                    if constexpr (ACCUM) v += Cf[ci];
                    Cf[ci] = v;
                }
            }
        }
    }
}

// ---------------- LayerNorm (bf16 out) ----------------
__global__ __launch_bounds__(64) void ln_kernel(const float* __restrict__ h,
                                                const float* __restrict__ w,
                                                const float* __restrict__ bgain,
                                                short* __restrict__ hn) {
    int m = blockIdx.x, lane = threadIdx.x;
    const float* row = h + (size_t)m * DM;
    float v[8]; float s = 0.f;
    #pragma unroll
    for (int j = 0; j < 8; j++) { v[j] = row[lane + j * 64]; s += v[j]; }
    for (int o = 1; o < 64; o <<= 1) s += __shfl_xor(s, o);
    float mu = s * (1.f / DM);
    float var = 0.f;
    #pragma unroll
    for (int j = 0; j < 8; j++) { float d = v[j] - mu; var += d * d; }
    for (int o = 1; o < 64; o <<= 1) var += __shfl_xor(var, o);
    float inv = rsqrtf(var * (1.f / DM) + 1e-5f);
    #pragma unroll
    for (int j = 0; j < 8; j++) {
        int c = lane + j * 64;
        hn[(size_t)m * DM + c] = f2b((v[j] - mu) * inv * w[c] + bgain[c]);
    }
}

// ---------------- depthwise conv (dir-aware) + SiLU ----------------
__global__ void conv_kernel(const float* __restrict__ zx2,
                            const float* __restrict__ cw,
                            const float* __restrict__ cb,
                            float* __restrict__ xbcc) {
    int idx = blockIdx.x * 256 + threadIdx.x;
    if (idx >= 2 * M2 * CONVD) return;
    int dir = idx / (M2 * CONVD);
    int r = idx - dir * (M2 * CONVD);
    int m = r / CONVD; int c = r - m * CONVD;
    int b = m / TOUT; int t = m - b * TOUT;
    float acc = cb[dir * CONVD + c];
    const float* w = cw + (size_t)(dir * CONVD + c) * 4;
    #pragma unroll
    for (int k = 0; k < 4; k++) {
        int tp = dir ? (t + 3 - k) : (t - 3 + k);
        if (tp >= 0 && tp < TOUT)
            acc += w[k] * zx2[(size_t)(b * TOUT + tp) * ZLD + dir * DINP + DIc + c];
    }
    xbcc[(size_t)idx] = acc / (1.f + expf(-acc));   // silu
}

// ---------------- dt softplus + dA ----------------
__global__ void dt_kernel(const float* __restrict__ zx2,
                          const float* __restrict__ dtB,
                          const float* __restrict__ alog,
                          float* __restrict__ dtb, float* __restrict__ dab) {
    int idx = blockIdx.x * 256 + threadIdx.x;
    if (idx >= 2 * M2 * Hh) return;
    int dir = idx / (M2 * Hh);
    int r = idx - dir * (M2 * Hh);
    int m = r / Hh; int hh = r - m * Hh;
    float raw = zx2[(size_t)m * ZLD + dir * DINP + DIc + CONVD + hh] + dtB[dir * Hh + hh];
    float sp = raw > 20.f ? raw : log1pf(expf(raw));
    float A = -expf(alog[dir * Hh + hh]);
    dtb[idx] = sp;
    dab[idx] = expf(sp * A);
}

// ---------------- chunked selective scan ----------------
__global__ __launch_bounds__(64) void scan_local(const float* __restrict__ xbcc,
                                                 const float* __restrict__ dtb,
                                                 const float* __restrict__ dab,
                                                 const float* __restrict__ Dp_pair,
                                                 float* __restrict__ ybuf,
                                                 float* __restrict__ Hbuf,
                                                 float* __restrict__ Pcum) {
    int h = blockIdx.x & 15, chunk = blockIdx.x >> 4;
    int b = blockIdx.y, dir = blockIdx.z;
    int lane = threadIdx.x;                 // lane = p (headdim)
    int s0 = chunk * LC;
    int s1 = min(s0 + LC, TOUT);
    __shared__ __align__(16) float bsh[2][64];
    __shared__ __align__(16) float csh[2][64];
    float st[64];
    #pragma unroll
    for (int n = 0; n < 64; n++) st[n] = 0.f;
    float Dpv = Dp_pair[dir * Hh + h];
    const float* xb = xbcc + (size_t)dir * M2 * CONVD;
    long dtbase = (size_t)(dir * M2 + b * TOUT) * Hh + h;
    int id = (dir * TB + b) * Hh + h;
    float* pcm = Pcum + (size_t)id * TOUT;

    int tt0 = dir ? (TOUT - 1 - s0) : s0;
    const float* row0 = xb + (size_t)(b * TOUT + tt0) * CONVD;
    float bcur = row0[DIc + lane];
    float ccur = row0[DIc + 64 + lane];
    float xcur = row0[h * 64 + lane];
    float dtcur = dtb[dtbase + (long)tt0 * Hh];
    float dacur = dab[dtbase + (long)tt0 * Hh];
    float P = 1.f;

    for (int s = s0; s < s1; s++) {
        int pb = s & 1;
        bsh[pb][lane] = bcur;
        csh[pb][lane] = ccur;
        float xp = xcur, dtt = dtcur, da = dacur;
        __syncthreads();
        if (s + 1 < s1) {
            int tn = dir ? (TOUT - 1 - (s + 1)) : (s + 1);
            const float* rown = xb + (size_t)(b * TOUT + tn) * CONVD;
            bcur = rown[DIc + lane];
            ccur = rown[DIc + 64 + lane];
            xcur = rown[h * 64 + lane];
            dtcur = dtb[dtbase + (long)tn * Hh];
            dacur = dab[dtbase + (long)tn * Hh];
        }
        float common = dtt * xp;
        float y0 = 0.f, y1 = 0.f, y2 = 0.f, y3 = 0.f;
        #pragma unroll
        for (int n4 = 0; n4 < 16; n4++) {
            float4 bv = ((const float4*)bsh[pb])[n4];
            float4 cv = ((const float4*)csh[pb])[n4];
            int n = n4 * 4;
            st[n]     = st[n]     * da + common * bv.x; y0 += st[n]     * cv.x;
            st[n + 1] = st[n + 1] * da + common * bv.y; y1 += st[n + 1] * cv.y;
            st[n + 2] = st[n + 2] * da + common * bv.z; y2 += st[n + 2] * cv.z;
            st[n + 3] = st[n + 3] * da + common * bv.w; y3 += st[n + 3] * cv.w;
        }
        int tt = dir ? (TOUT - 1 - s) : s;
        int m = b * TOUT + tt;
        ybuf[((size_t)dir * M2 + m) * DIc + h * 64 + lane] = (y0 + y1) + (y2 + y3) + Dpv * xp;
        P *= da;
        if (lane == 0) pcm[s] = P;
    }
    float* Ho = Hbuf + (((size_t)id * NC + chunk) * 64 + lane) * 64;
    #pragma unroll
    for (int n4 = 0; n4 < 16; n4++) {
        ((float4*)Ho)[n4] = (float4){st[n4 * 4], st[n4 * 4 + 1], st[n4 * 4 + 2], st[n4 * 4 + 3]};
    }
}

__global__ __launch_bounds__(64) void scan_combine(float* __restrict__ Hbuf,
                                                   const float* __restrict__ Pcum) {
    int id = blockIdx.x;
    int lane = threadIdx.x;
    float Hin[64];
    #pragma unroll
    for (int n = 0; n < 64; n++) Hin[n] = 0.f;
    const float* pcm = Pcum + (size_t)id * TOUT;
    for (int c = 0; c < NC; c++) {
        float* Hp = Hbuf + (((size_t)id * NC + c) * 64 + lane) * 64;
        float Hout[64];
        #pragma unroll
        for (int n4 = 0; n4 < 16; n4++) {
            float4 v = ((const float4*)Hp)[n4];
            Hout[n4 * 4] = v.x; Hout[n4 * 4 + 1] = v.y;
            Hout[n4 * 4 + 2] = v.z; Hout[n4 * 4 + 3] = v.w;
        }
        #pragma unroll
        for (int n4 = 0; n4 < 16; n4++)
            ((float4*)Hp)[n4] = (float4){Hin[n4 * 4], Hin[n4 * 4 + 1], Hin[n4 * 4 + 2], Hin[n4 * 4 + 3]};
        int send = min((c + 1) * LC, TOUT) - 1;
        float Pe = pcm[send];
        #pragma unroll
        for (int n = 0; n < 64; n++) Hin[n] = Hout[n] + Pe * Hin[n];
    }
}

__global__ __launch_bounds__(64) void scan_fix(const float* __restrict__ xbcc,
                                               const float* __restrict__ Hbuf,
                                               const float* __restrict__ Pcum,
                                               float* __restrict__ ybuf) {
    int h = blockIdx.x & 15;
    int q = (blockIdx.x >> 4) & 3;
    int c = 1 + (blockIdx.x >> 6);
    int b = blockIdx.y, dir = blockIdx.z, lane = threadIdx.x;
    int s0 = c * LC;
    int s1 = min(s0 + LC, TOUT);
    int sa = s0 + q * (LC / 4);
    int se = min(sa + LC / 4, s1);
    if (sa >= se) return;
    int id = (dir * TB + b) * Hh + h;
    float Hr[64];
    const float* Hp = Hbuf + (((size_t)id * NC + c) * 64 + lane) * 64;
    #pragma unroll
    for (int n4 = 0; n4 < 16; n4++) {
        float4 v = ((const float4*)Hp)[n4];
        Hr[n4 * 4] = v.x; Hr[n4 * 4 + 1] = v.y; Hr[n4 * 4 + 2] = v.z; Hr[n4 * 4 + 3] = v.w;
    }
    const float* pcm = Pcum + (size_t)id * TOUT;
    const float* xb = xbcc + (size_t)dir * M2 * CONVD;
    for (int s = sa; s < se; s++) {
        int tt = dir ? (TOUT - 1 - s) : s;
        const float4* crow = (const float4*)(xb + (size_t)(b * TOUT + tt) * CONVD + DIc + 64);
        float acc = 0.f;
        #pragma unroll
        for (int n4 = 0; n4 < 16; n4++) {
            float4 cv = crow[n4];
            acc += Hr[n4 * 4] * cv.x + Hr[n4 * 4 + 1] * cv.y
                 + Hr[n4 * 4 + 2] * cv.z + Hr[n4 * 4 + 3] * cv.w;
        }
        size_t yi = ((size_t)dir * M2 + b * TOUT + tt) * DIc + h * 64 + lane;
        ybuf[yi] += pcm[s] * acc;
    }
}

// ---------------- gate (silu(z)) + RMSNorm -> bf16 fw|bw interleaved rows ----------------
__global__ __launch_bounds__(64) void grms_kernel(const float* __restrict__ ybuf,
                                                  const float* __restrict__ zx2,
                                                  const float* __restrict__ nw,
                                                  short* __restrict__ yo) {
    int m = blockIdx.x, dir = blockIdx.y, lane = threadIdx.x;
    const float* y = ybuf + ((size_t)dir * M2 + m) * DIc;
    const float* z = zx2 + (size_t)m * ZLD + dir * DINP;
    float g[16]; float ss = 0.f;
    #pragma unroll
    for (int j = 0; j < 16; j++) {
        int c = lane + j * 64;
        float zv = z[c];
        float gv = y[c] * (zv / (1.f + expf(-zv)));
        g[j] = gv; ss += gv * gv;
    }
    for (int o = 1; o < 64; o <<= 1) ss += __shfl_xor(ss, o);
    float sc = rsqrtf(ss * (1.f / DIc) + 1e-5f);
    #pragma unroll
    for (int j = 0; j < 16; j++) {
        int c = lane + j * 64;
        yo[(size_t)m * (2 * DIc) + dir * DIc + c] = f2b(g[j] * sc * nw[dir * DIc + c]);
    }
}

// ---------------- final classifier head (fp32 output) ----------------
__global__ __launch_bounds__(64) void outk(const float* __restrict__ h,
                                           const float* __restrict__ ow,
                                           const float* __restrict__ ob,
                                           float* __restrict__ out) {
    int m = blockIdx.x, lane = threadIdx.x;
    __shared__ float hs[DM];
    #pragma unroll
    for (int j = 0; j < 8; j++) hs[lane + j * 64] = h[(size_t)m * DM + lane + j * 64];
    __syncthreads();
    if (lane < 41) {
        float acc = ob[lane];
        for (int d = 0; d < DM; d++) acc += hs[d] * ow[lane * DM + d];
        out[(size_t)m * 41 + lane] = acc;
    }
}

// ---------------- launch ----------------
extern "C" void kernel_launch(void* const* d_in, const int* in_sizes, int n_in,
                              void* d_out, int out_size, void* d_ws, size_t ws_size,
                              hipStream_t stream) {
    const float* x        = (const float*)d_in[0];
    const int*   day_idx  = (const int*)d_in[1];
    const float* day_w    = (const float*)d_in[2];
    const float* day_b    = (const float*)d_in[3];
    const float* w1       = (const float*)d_in[4];
    const float* b1       = (const float*)d_in[5];
    const float* w2       = (const float*)d_in[6];
    const float* b2       = (const float*)d_in[7];
    const float* ln_w     = (const float*)d_in[8];
    const float* ln_b     = (const float*)d_in[9];
    const float* m_in_w   = (const float*)d_in[10];
    const float* m_conv_w = (const float*)d_in[11];
    const float* m_conv_b = (const float*)d_in[12];
    const float* m_dt     = (const float*)d_in[13];
    const float* m_Alog   = (const float*)d_in[14];
    const float* m_D      = (const float*)d_in[15];
    const float* m_norm_w = (const float*)d_in[16];
    const float* m_out_w  = (const float*)d_in[17];
    const float* out_w    = (const float*)d_in[18];
    const float* out_b    = (const float*)d_in[19];

    float* ws = (float*)d_ws;
    // ---- prologue overlay ----
    short* hfb  = (short*)ws;                  // [4][2048][513] bf16    = 2,101,248 f
    short* Apad = (short*)(ws + 2101248);      // [2036][7200] bf16      = 7,329,600 f -> ends 9,430,848
    short* B1h  = (short*)(ws + 9430848);      // [2048][7200] bf16      = 7,372,800 f -> ends 16,803,648
    short* h1b  = (short*)(ws + 16803648);     // [2036][4096] bf16      = 4,169,728 f -> ends 20,973,376
    short* w2b  = (short*)(ws + 20973376);     // [512][4096] bf16       = 1,048,576 f -> ends 22,021,952
    // ---- persistent ----
    float* hbuf = ws + 22021952;               // [2036][512]            = 1,042,432 f -> ends 23,064,384
    short* hnb  = (short*)(ws + 23064384);     // [2036][512] bf16       = 521,216 f   -> ends 23,585,600
    // ---- loop overlay (reuses [0, 22,021,952)) ----
    float* zx2  = ws;                          // [2036][4384]           = 8,925,824 f
    float* xbcc = ws + 8925824;                // [2][2036][1152]        = 4,690,944 f
    short* ybf  = (short*)(ws + 8925824);      // [2036][2048] bf16 (overlays dead xbcc)
    float* ybuf = ws + 13616768;               // [2][2036][1024]        = 4,169,728 f
    float* Hbuf = ws + 17786496;               // [128][NC][64][64]      = 2,097,152 f
    float* Pcum = ws + 19883648;               // [128][509]             = 65,152 f
    float* dtb  = ws + 19948800;               // 65,152 f
    float* dab  = ws + 20013952;               // 65,152 f
    short* inwb = (short*)(ws + 20079104);     // [4384][512] bf16       = 1,122,304 f -> ends 21,201,408
    short* outwb= (short*)(ws + 21201408);     // [512][2048] bf16       = 524,288 f   -> ends 21,725,696

    day_gemm<<<dim3(8, 32, 4), 256, 0, stream>>>(x, day_idx, day_w, day_b, hfb);
    copy_xt<<<32, 256, 0, stream>>>(x, hfb);
    expand_patches<<<M2, 256, 0, stream>>>(hfb, Apad);
    cvtk<<<2048, 256, 0, stream>>>(w2, w2b, (long)512 * PR);
    // patch-projection GEMM in two N-halves (B1h converted per half)
    for (int half = 0; half < 2; half++) {
        cvt_w1<<<7200, 256, 0, stream>>>(w1 + (size_t)half * 2048 * KW1, B1h, 2048);
        bgemm<1, 0, 1, 0><<<dim3(16, 16), 256, 0, stream>>>(
            Apad, B1h, b1 + half * 2048, h1b + half * 2048,
            M2, 2048, KP1, 1, (long)KP1, 0L, PR);
    }
    // w2 GEMM: bias prefill + split-K atomic accumulate (K=4096 -> 4 slices)
    fillb<<<(M2 * DM + 255) / 256, 256, 0, stream>>>(hbuf, b2, M2 * DM, DM);
    bgemm<0, 0, 0, 1><<<dim3(4, 16, 4), 256, 0, stream>>>(h1b, w2b, nullptr, hbuf,
                                                          M2, DM, PR, 1, (long)PR, 0L, DM);
    for (int i = 0; i < 5; i++) {
        ln_kernel<<<M2, 64, 0, stream>>>(hbuf, ln_w + i * DM, ln_b + i * DM, hnb);
        cvtk<<<2192, 256, 0, stream>>>(m_in_w + (size_t)2 * i * DINP * DM, inwb, (long)2 * DINP * DM);
        bgemm<0, 0, 0, 0><<<dim3(35, 16), 256, 0, stream>>>(hnb, inwb, nullptr, zx2,
                                                            M2, ZLD, DM, 1, (long)DM, 0L, ZLD);
        conv_kernel<<<(2 * M2 * CONVD + 255) / 256, 256, 0, stream>>>(
            zx2, m_conv_w + (size_t)2 * i * CONVD * 4, m_conv_b + (size_t)2 * i * CONVD, xbcc);
        dt_kernel<<<(2 * M2 * Hh + 255) / 256, 256, 0, stream>>>(
            zx2, m_dt + 2 * i * Hh, m_Alog + 2 * i * Hh, dtb, dab);
        scan_local<<<dim3(Hh * NC, TB, 2), 64, 0, stream>>>(xbcc, dtb, dab, m_D + 2 * i * Hh,
                                                            ybuf, Hbuf, Pcum);
        scan_combine<<<128, 64, 0, stream>>>(Hbuf, Pcum);
        scan_fix<<<dim3(Hh * 4 * (NC - 1), TB, 2), 64, 0, stream>>>(xbcc, Hbuf, Pcum, ybuf);
        grms_kernel<<<dim3(M2, 2), 64, 0, stream>>>(ybuf, zx2, m_norm_w + (size_t)2 * i * DIc, ybf);
        cvt_outw<<<1024, 256, 0, stream>>>(m_out_w + (size_t)(2 * i) * DM * DIc,
                                           m_out_w + (size_t)(2 * i + 1) * DM * DIc, outwb);
        // merged fw+bw out-projection, split-K atomic accumulate onto residual (K=2048 -> 4 slices)
        bgemm<0, 0, 0, 1><<<dim3(4, 16, 4), 256, 0, stream>>>(ybf, outwb, nullptr, hbuf,
                                                              M2, DM, 2 * DIc, 1, (long)(2 * DIc), 0L, DM);
    }
    outk<<<M2, 64, 0, stream>>>(hbuf, out_w, out_b, (float*)d_out);
}

// Round 5
// 2020.608 us; speedup vs baseline: 1.4563x; 1.0788x over previous
//
#include <hip/hip_runtime.h>

// ---------------- constants ----------------
#define TB 4
#define TT 2048
#define DIN 513
#define TOUT 509
#define M2 2036          // TB*TOUT
#define DM 512
#define PR 4096
#define DIc 1024
#define Hh 16
#define CONVD 1152
#define DINP 2192        // 2*DIc + 2*64 + 16
#define ZLD 4384         // 2*DINP (fw|bw stacked)
#define LC 128           // scan chunk length
#define NC 4             // ceil(TOUT/LC)
#define KW1 7182         // true K of patch GEMM
#define KP1 7200         // K padded to mult of 32

typedef __attribute__((ext_vector_type(8))) short s8v;   // 8 bf16 in 4 VGPRs
typedef __attribute__((ext_vector_type(4))) float f4v;   // MFMA accumulator

__device__ __forceinline__ short f2b(float f) {          // fp32 -> bf16 RNE
    unsigned u = __float_as_uint(f);
    u += 0x7fffu + ((u >> 16) & 1u);
    return (short)(u >> 16);
}

// async global->LDS DMA. LDS dest is wave-uniform base + lane*size; global src is per-lane.
__device__ __forceinline__ void gld16(const void* g, void* l) {
    __builtin_amdgcn_global_load_lds(
        (const __attribute__((address_space(1))) unsigned int*)g,
        (__attribute__((address_space(3))) unsigned int*)l, 16, 0, 0);
}
__device__ __forceinline__ void gld4(const void* g, void* l) {
    __builtin_amdgcn_global_load_lds(
        (const __attribute__((address_space(1))) unsigned int*)g,
        (__attribute__((address_space(3))) unsigned int*)l, 4, 0, 0);
}

// ---------------- day-specific input transform (fp32 tiled, bf16 out) ----------------
__global__ __launch_bounds__(256) void day_gemm(const float* __restrict__ x,
                                                const int* __restrict__ day_idx,
                                                const float* __restrict__ day_w,
                                                const float* __restrict__ day_b,
                                                short* __restrict__ hfull) {
    int b = blockIdx.z;
    int day = day_idx[b];
    int n0 = blockIdx.x * 64, m0 = blockIdx.y * 64;
    int tid = threadIdx.x;
    __shared__ float As[16][68], Bs[16][68];
    float acc[4][4] = {};
    int tm = tid >> 4, tn = tid & 15;
    int lrow = tid >> 2, lk = (tid & 3) * 4;
    const float* Ab = x + ((size_t)b * TT + m0) * DIN;
    const float* Bb = day_w + (size_t)day * 512 * 512;
    for (int k0 = 0; k0 < 512; k0 += 16) {
        #pragma unroll
        for (int j = 0; j < 4; j++)
            As[lk + j][lrow] = Ab[(size_t)lrow * DIN + k0 + lk + j];
        int kb = tid >> 4; int nb = (tid & 15) * 4;
        #pragma unroll
        for (int j = 0; j < 4; j++)
            Bs[kb][nb + j] = Bb[(size_t)(k0 + kb) * 512 + n0 + nb + j];
        __syncthreads();
        #pragma unroll
        for (int kk = 0; kk < 16; kk++) {
            float4 av = *(const float4*)&As[kk][tm * 4];
            float4 bv = *(const float4*)&Bs[kk][tn * 4];
            float a[4] = {av.x, av.y, av.z, av.w};
            float bb2[4] = {bv.x, bv.y, bv.z, bv.w};
            #pragma unroll
            for (int i = 0; i < 4; i++)
                #pragma unroll
                for (int j = 0; j < 4; j++) acc[i][j] += a[i] * bb2[j];
        }
        __syncthreads();
    }
    #pragma unroll
    for (int i = 0; i < 4; i++) {
        int m = m0 + tm * 4 + i;
        #pragma unroll
        for (int j = 0; j < 4; j++) {
            int n = n0 + tn * 4 + j;
            float v = acc[i][j] + day_b[day * 512 + n];
            v = v / (1.f + fabsf(v));
            hfull[((size_t)b * TT + m) * DIN + n] = f2b(v);
        }
    }
}

__global__ void copy_xt(const float* __restrict__ x, short* __restrict__ hfull) {
    int idx = blockIdx.x * 256 + threadIdx.x;
    if (idx >= TB * TT) return;
    hfull[(size_t)idx * DIN + 512] = f2b(x[(size_t)idx * DIN + 512]);
}

// ---------------- conversion kernels ----------------
// w1 [4096][7182] fp32 -> [4096][7200] bf16, zero-padded tail (rows only 8B-aligned -> float2)
__global__ void cvt_w1(const float* __restrict__ s, short* __restrict__ d) {
    long idx = (long)blockIdx.x * 256 + threadIdx.x;      // 4096*900 threads, 8 elems each
    if (idx >= (long)4096 * 900) return;
    int row = (int)(idx / 900);
    int kc = (int)(idx % 900) * 8;
    const float* src = s + (long)row * KW1 + kc;
    short* dst = d + (long)row * KP1 + kc;
    if (kc + 8 <= KW1) {
        const float2* s2 = (const float2*)src;
        #pragma unroll
        for (int j = 0; j < 4; j++) {
            float2 u = s2[j];
            dst[2 * j] = f2b(u.x); dst[2 * j + 1] = f2b(u.y);
        }
    } else {
        #pragma unroll
        for (int j = 0; j < 8; j++)
            dst[j] = (kc + j < KW1) ? f2b(src[j]) : (short)0;
    }
}

// generic fp32 -> bf16, n multiple of 4
__global__ void cvtk(const float* __restrict__ s, short* __restrict__ d, long n) {
    long i = ((long)blockIdx.x * 256 + threadIdx.x) * 4;
    if (i >= n) return;
    float4 v = *(const float4*)(s + i);
    d[i] = f2b(v.x); d[i + 1] = f2b(v.y); d[i + 2] = f2b(v.z); d[i + 3] = f2b(v.w);
}

// pack fw|bw out-proj weights: d[n][k], k<1024 from fw[n][k], else bw[n][k-1024]
__global__ void cvt_outw(const float* __restrict__ fw, const float* __restrict__ bw,
                         short* __restrict__ d) {
    long idx = (long)blockIdx.x * 256 + threadIdx.x;      // 512*2048/4
    if (idx >= (long)512 * 512) return;
    long e = idx * 4;
    int n = (int)(e >> 11);
    int k = (int)(e & 2047);
    const float* src = (k < 1024) ? (fw + (long)n * 1024 + k)
                                  : (bw + (long)n * 1024 + (k - 1024));
    float4 v = *(const float4*)src;
    short* dst = d + e;
    dst[0] = f2b(v.x); dst[1] = f2b(v.y); dst[2] = f2b(v.z); dst[3] = f2b(v.w);
}

// fill C with broadcast bias (pre-pass for atomic split-K)
__global__ void fillb(float* __restrict__ dst, const float* __restrict__ b, int total, int N) {
    int idx = blockIdx.x * 256 + threadIdx.x;
    if (idx >= total) return;
    dst[idx] = b[idx & (N - 1)];
}

// ---------------- bf16 MFMA GEMM, global_load_lds staging (m97 structure) ----------------
// A: bf16, row m at (m/rowDiv)*sOuter + (m%rowDiv)*sInner (element units), K contiguous.
// Bw: bf16 [N][K], rows 16B-aligned. K multiple of 32.
// AW=16: A rows 16B-aligned (2x gld16/wave). AW=4: only 4B-aligned (8x gld4/wave).
// ATOMIC=1: split-K over gridDim.z, partial sums via unsafeAtomicAdd (bias null, ACT=0).
template <int ACT, int ACCUM, int OUTBF, int ATOMIC, int AW>
__global__ __launch_bounds__(256) void bgemm(const short* __restrict__ A,
                                             const short* __restrict__ Bw,
                                             const float* __restrict__ bias,
                                             void* __restrict__ Cout,
                                             int M, int N, int K,
                                             int rowDiv, long sOuter, long sInner, int ldc) {
    __shared__ short As[128 * 32];
    __shared__ short Bs[128 * 32];
    // bijective XCD-aware swizzle (m204): per-XCD contiguous chunks of the grid
    int nwg = gridDim.x * gridDim.y;
    int orig = blockIdx.y * gridDim.x + blockIdx.x;
    int q = nwg >> 3, rr = nwg & 7;
    int xcd = orig & 7, ii = orig >> 3;
    int wg = (xcd < rr ? xcd * (q + 1) : rr * (q + 1) + (xcd - rr) * q) + ii;
    int bx = wg % gridDim.x, by = wg / gridDim.x;
    int m0 = by * 128, n0 = bx * 128;

    int tid = threadIdx.x;
    int wave = tid >> 6, lane = tid & 63;
    int wm = (wave & 1) * 64, wn = (wave >> 1) * 64;
    int lm = lane & 15, quad = lane >> 4;

    const short* Ap[(AW == 4) ? 8 : 2];
    if constexpr (AW == 4) {
        int kcc = (lane & 15) * 2;                        // 4B chunk within 32-col row
        #pragma unroll
        for (int c = 0; c < 8; c++) {
            int r = m0 + wave * 32 + c * 4 + (lane >> 4);
            r = min(r, M - 1);
            Ap[c] = A + (long)(r / rowDiv) * sOuter + (long)(r % rowDiv) * sInner + kcc;
        }
    } else {
        int kca = (lane & 3) * 8;                         // 16B chunk within 32-col row
        int r0 = min(m0 + wave * 32 + (lane >> 2), M - 1);
        int r1 = min(m0 + wave * 32 + 16 + (lane >> 2), M - 1);
        Ap[0] = A + (long)(r0 / rowDiv) * sOuter + (long)(r0 % rowDiv) * sInner + kca;
        Ap[1] = A + (long)(r1 / rowDiv) * sOuter + (long)(r1 % rowDiv) * sInner + kca;
    }
    int kcb = (lane & 3) * 8;
    int b0 = min(n0 + wave * 32 + (lane >> 2), N - 1);
    int b1 = min(n0 + wave * 32 + 16 + (lane >> 2), N - 1);
    const short* Bp0 = Bw + (long)b0 * K + kcb;
    const short* Bp1 = Bw + (long)b1 * K + kcb;
    short* lA = As + wave * 1024;                         // rows [wave*32, wave*32+32)
    short* lB = Bs + wave * 1024;

    f4v acc[4][4];
    #pragma unroll
    for (int i = 0; i < 4; i++)
        #pragma unroll
        for (int j = 0; j < 4; j++) acc[i][j] = (f4v){0.f, 0.f, 0.f, 0.f};

    int kper = K, kbeg = 0;
    if constexpr (ATOMIC) { kper = K / (int)gridDim.z; kbeg = blockIdx.z * kper; }
    for (int k0 = kbeg; k0 < kbeg + kper; k0 += 32) {
        if constexpr (AW == 4) {
            #pragma unroll
            for (int c = 0; c < 8; c++)
                gld4(Ap[c] + k0, lA + c * 128);
        } else {
            gld16(Ap[0] + k0, lA);
            gld16(Ap[1] + k0, lA + 512);
        }
        gld16(Bp0 + k0, lB);
        gld16(Bp1 + k0, lB + 512);
        __syncthreads();                                  // waits vmcnt(0): tiles landed
        s8v af[4], bf[4];
        #pragma unroll
        for (int i = 0; i < 4; i++)
            af[i] = *(const s8v*)&As[(wm + i * 16 + lm) * 32 + quad * 8];
        #pragma unroll
        for (int j = 0; j < 4; j++)
            bf[j] = *(const s8v*)&Bs[(wn + j * 16 + lm) * 32 + quad * 8];
        #pragma unroll
        for (int i = 0; i < 4; i++)
            #pragma unroll
            for (int j = 0; j < 4; j++)
                acc[i][j] = __builtin_amdgcn_mfma_f32_16x16x32_bf16(af[i], bf[j], acc[i][j], 0, 0, 0);
        __syncthreads();                                  // all reads done before restage
    }

    #pragma unroll
    for (int i = 0; i < 4; i++) {
        #pragma unroll
        for (int e = 0; e < 4; e++) {
            int m = m0 + wm + i * 16 + quad * 4 + e;
            if (m >= M) continue;
            #pragma unroll
            for (int j = 0; j < 4; j++) {
                int n = n0 + wn + j * 16 + lm;
                if (n >= N) continue;
                float v = acc[i][j][e];
                if (bias) v += bias[n];
                if (ACT == 1) v = v / (1.f + fabsf(v));
                long ci = (long)m * ldc + n;
                if constexpr (OUTBF) {
                    ((short*)Cout)[ci] = f2b(v);
                } else if constexpr (ATOMIC) {
                    unsafeAtomicAdd(&((float*)Cout)[ci], v);
                } else {
                    float* Cf = (float*)Cout;
                    if constexpr (ACCUM) v += Cf[ci];
                    Cf[ci] = v;
                }
            }
        }
    }
}

// ---------------- LayerNorm (bf16 out) ----------------
__global__ __launch_bounds__(64) void ln_kernel(const float* __restrict__ h,
                                                const float* __restrict__ w,
                                                const float* __restrict__ bgain,
                                                short* __restrict__ hn) {
    int m = blockIdx.x, lane = threadIdx.x;
    const float* row = h + (size_t)m * DM;
    float v[8]; float s = 0.f;
    #pragma unroll
    for (int j = 0; j < 8; j++) { v[j] = row[lane + j * 64]; s += v[j]; }
    for (int o = 1; o < 64; o <<= 1) s += __shfl_xor(s, o);
    float mu = s * (1.f / DM);
    float var = 0.f;
    #pragma unroll
    for (int j = 0; j < 8; j++) { float d = v[j] - mu; var += d * d; }
    for (int o = 1; o < 64; o <<= 1) var += __shfl_xor(var, o);
    float inv = rsqrtf(var * (1.f / DM) + 1e-5f);
    #pragma unroll
    for (int j = 0; j < 8; j++) {
        int c = lane + j * 64;
        hn[(size_t)m * DM + c] = f2b((v[j] - mu) * inv * w[c] + bgain[c]);
    }
}

// ---------------- depthwise conv (dir-aware) + SiLU ----------------
__global__ void conv_kernel(const float* __restrict__ zx2,
                            const float* __restrict__ cw,
                            const float* __restrict__ cb,
                            float* __restrict__ xbcc) {
    int idx = blockIdx.x * 256 + threadIdx.x;
    if (idx >= 2 * M2 * CONVD) return;
    int dir = idx / (M2 * CONVD);
    int r = idx - dir * (M2 * CONVD);
    int m = r / CONVD; int c = r - m * CONVD;
    int b = m / TOUT; int t = m - b * TOUT;
    float acc = cb[dir * CONVD + c];
    const float* w = cw + (size_t)(dir * CONVD + c) * 4;
    #pragma unroll
    for (int k = 0; k < 4; k++) {
        int tp = dir ? (t + 3 - k) : (t - 3 + k);
        if (tp >= 0 && tp < TOUT)
            acc += w[k] * zx2[(size_t)(b * TOUT + tp) * ZLD + dir * DINP + DIc + c];
    }
    xbcc[(size_t)idx] = acc / (1.f + expf(-acc));   // silu
}

// ---------------- dt softplus + dA ----------------
__global__ void dt_kernel(const float* __restrict__ zx2,
                          const float* __restrict__ dtB,
                          const float* __restrict__ alog,
                          float* __restrict__ dtb, float* __restrict__ dab) {
    int idx = blockIdx.x * 256 + threadIdx.x;
    if (idx >= 2 * M2 * Hh) return;
    int dir = idx / (M2 * Hh);
    int r = idx - dir * (M2 * Hh);
    int m = r / Hh; int hh = r - m * Hh;
    float raw = zx2[(size_t)m * ZLD + dir * DINP + DIc + CONVD + hh] + dtB[dir * Hh + hh];
    float sp = raw > 20.f ? raw : log1pf(expf(raw));
    float A = -expf(alog[dir * Hh + hh]);
    dtb[idx] = sp;
    dab[idx] = expf(sp * A);
}

// ---------------- chunked selective scan ----------------
__global__ __launch_bounds__(64) void scan_local(const float* __restrict__ xbcc,
                                                 const float* __restrict__ dtb,
                                                 const float* __restrict__ dab,
                                                 const float* __restrict__ Dp_pair,
                                                 float* __restrict__ ybuf,
                                                 float* __restrict__ Hbuf,
                                                 float* __restrict__ Pcum) {
    int h = blockIdx.x & 15, chunk = blockIdx.x >> 4;
    int b = blockIdx.y, dir = blockIdx.z;
    int lane = threadIdx.x;                 // lane = p (headdim)
    int s0 = chunk * LC;
    int s1 = min(s0 + LC, TOUT);
    __shared__ __align__(16) float bsh[2][64];
    __shared__ __align__(16) float csh[2][64];
    float st[64];
    #pragma unroll
    for (int n = 0; n < 64; n++) st[n] = 0.f;
    float Dpv = Dp_pair[dir * Hh + h];
    const float* xb = xbcc + (size_t)dir * M2 * CONVD;
    long dtbase = (size_t)(dir * M2 + b * TOUT) * Hh + h;
    int id = (dir * TB + b) * Hh + h;
    float* pcm = Pcum + (size_t)id * TOUT;

    int tt0 = dir ? (TOUT - 1 - s0) : s0;
    const float* row0 = xb + (size_t)(b * TOUT + tt0) * CONVD;
    float bcur = row0[DIc + lane];
    float ccur = row0[DIc + 64 + lane];
    float xcur = row0[h * 64 + lane];
    float dtcur = dtb[dtbase + (long)tt0 * Hh];
    float dacur = dab[dtbase + (long)tt0 * Hh];
    float P = 1.f;

    for (int s = s0; s < s1; s++) {
        int pb = s & 1;
        bsh[pb][lane] = bcur;
        csh[pb][lane] = ccur;
        float xp = xcur, dtt = dtcur, da = dacur;
        __syncthreads();
        if (s + 1 < s1) {
            int tn = dir ? (TOUT - 1 - (s + 1)) : (s + 1);
            const float* rown = xb + (size_t)(b * TOUT + tn) * CONVD;
            bcur = rown[DIc + lane];
            ccur = rown[DIc + 64 + lane];
            xcur = rown[h * 64 + lane];
            dtcur = dtb[dtbase + (long)tn * Hh];
            dacur = dab[dtbase + (long)tn * Hh];
        }
        float common = dtt * xp;
        float y0 = 0.f, y1 = 0.f, y2 = 0.f, y3 = 0.f;
        #pragma unroll
        for (int n4 = 0; n4 < 16; n4++) {
            float4 bv = ((const float4*)bsh[pb])[n4];
            float4 cv = ((const float4*)csh[pb])[n4];
            int n = n4 * 4;
            st[n]     = st[n]     * da + common * bv.x; y0 += st[n]     * cv.x;
            st[n + 1] = st[n + 1] * da + common * bv.y; y1 += st[n + 1] * cv.y;
            st[n + 2] = st[n + 2] * da + common * bv.z; y2 += st[n + 2] * cv.z;
            st[n + 3] = st[n + 3] * da + common * bv.w; y3 += st[n + 3] * cv.w;
        }
        int tt = dir ? (TOUT - 1 - s) : s;
        int m = b * TOUT + tt;
        ybuf[((size_t)dir * M2 + m) * DIc + h * 64 + lane] = (y0 + y1) + (y2 + y3) + Dpv * xp;
        P *= da;
        if (lane == 0) pcm[s] = P;
    }
    float* Ho = Hbuf + (((size_t)id * NC + chunk) * 64 + lane) * 64;
    #pragma unroll
    for (int n4 = 0; n4 < 16; n4++) {
        ((float4*)Ho)[n4] = (float4){st[n4 * 4], st[n4 * 4 + 1], st[n4 * 4 + 2], st[n4 * 4 + 3]};
    }
}

__global__ __launch_bounds__(64) void scan_combine(float* __restrict__ Hbuf,
                                                   const float* __restrict__ Pcum) {
    int id = blockIdx.x;
    int lane = threadIdx.x;
    float Hin[64];
    #pragma unroll
    for (int n = 0; n < 64; n++) Hin[n] = 0.f;
    const float* pcm = Pcum + (size_t)id * TOUT;
    for (int c = 0; c < NC; c++) {
        float* Hp = Hbuf + (((size_t)id * NC + c) * 64 + lane) * 64;
        float Hout[64];
        #pragma unroll
        for (int n4 = 0; n4 < 16; n4++) {
            float4 v = ((const float4*)Hp)[n4];
            Hout[n4 * 4] = v.x; Hout[n4 * 4 + 1] = v.y;
            Hout[n4 * 4 + 2] = v.z; Hout[n4 * 4 + 3] = v.w;
        }
        #pragma unroll
        for (int n4 = 0; n4 < 16; n4++)
            ((float4*)Hp)[n4] = (float4){Hin[n4 * 4], Hin[n4 * 4 + 1], Hin[n4 * 4 + 2], Hin[n4 * 4 + 3]};
        int send = min((c + 1) * LC, TOUT) - 1;
        float Pe = pcm[send];
        #pragma unroll
        for (int n = 0; n < 64; n++) Hin[n] = Hout[n] + Pe * Hin[n];
    }
}

__global__ __launch_bounds__(64) void scan_fix(const float* __restrict__ xbcc,
                                               const float* __restrict__ Hbuf,
                                               const float* __restrict__ Pcum,
                                               float* __restrict__ ybuf) {
    int h = blockIdx.x & 15;
    int q = (blockIdx.x >> 4) & 3;
    int c = 1 + (blockIdx.x >> 6);
    int b = blockIdx.y, dir = blockIdx.z, lane = threadIdx.x;
    int s0 = c * LC;
    int s1 = min(s0 + LC, TOUT);
    int sa = s0 + q * (LC / 4);
    int se = min(sa + LC / 4, s1);
    if (sa >= se) return;
    int id = (dir * TB + b) * Hh + h;
    float Hr[64];
    const float* Hp = Hbuf + (((size_t)id * NC + c) * 64 + lane) * 64;
    #pragma unroll
    for (int n4 = 0; n4 < 16; n4++) {
        float4 v = ((const float4*)Hp)[n4];
        Hr[n4 * 4] = v.x; Hr[n4 * 4 + 1] = v.y; Hr[n4 * 4 + 2] = v.z; Hr[n4 * 4 + 3] = v.w;
    }
    const float* pcm = Pcum + (size_t)id * TOUT;
    const float* xb = xbcc + (size_t)dir * M2 * CONVD;
    for (int s = sa; s < se; s++) {
        int tt = dir ? (TOUT - 1 - s) : s;
        const float4* crow = (const float4*)(xb + (size_t)(b * TOUT + tt) * CONVD + DIc + 64);
        float acc = 0.f;
        #pragma unroll
        for (int n4 = 0; n4 < 16; n4++) {
            float4 cv = crow[n4];
            acc += Hr[n4 * 4] * cv.x + Hr[n4 * 4 + 1] * cv.y
                 + Hr[n4 * 4 + 2] * cv.z + Hr[n4 * 4 + 3] * cv.w;
        }
        size_t yi = ((size_t)dir * M2 + b * TOUT + tt) * DIc + h * 64 + lane;
        ybuf[yi] += pcm[s] * acc;
    }
}

// ---------------- gate (silu(z)) + RMSNorm -> bf16 fw|bw interleaved rows ----------------
__global__ __launch_bounds__(64) void grms_kernel(const float* __restrict__ ybuf,
                                                  const float* __restrict__ zx2,
                                                  const float* __restrict__ nw,
                                                  short* __restrict__ yo) {
    int m = blockIdx.x, dir = blockIdx.y, lane = threadIdx.x;
    const float* y = ybuf + ((size_t)dir * M2 + m) * DIc;
    const float* z = zx2 + (size_t)m * ZLD + dir * DINP;
    float g[16]; float ss = 0.f;
    #pragma unroll
    for (int j = 0; j < 16; j++) {
        int c = lane + j * 64;
        float zv = z[c];
        float gv = y[c] * (zv / (1.f + expf(-zv)));
        g[j] = gv; ss += gv * gv;
    }
    for (int o = 1; o < 64; o <<= 1) ss += __shfl_xor(ss, o);
    float sc = rsqrtf(ss * (1.f / DIc) + 1e-5f);
    #pragma unroll
    for (int j = 0; j < 16; j++) {
        int c = lane + j * 64;
        yo[(size_t)m * (2 * DIc) + dir * DIc + c] = f2b(g[j] * sc * nw[dir * DIc + c]);
    }
}

// ---------------- final classifier head (fp32 output) ----------------
__global__ __launch_bounds__(64) void outk(const float* __restrict__ h,
                                           const float* __restrict__ ow,
                                           const float* __restrict__ ob,
                                           float* __restrict__ out) {
    int m = blockIdx.x, lane = threadIdx.x;
    __shared__ float hs[DM];
    #pragma unroll
    for (int j = 0; j < 8; j++) hs[lane + j * 64] = h[(size_t)m * DM + lane + j * 64];
    __syncthreads();
    if (lane < 41) {
        float acc = ob[lane];
        for (int d = 0; d < DM; d++) acc += hs[d] * ow[lane * DM + d];
        out[(size_t)m * 41 + lane] = acc;
    }
}

// ---------------- launch ----------------
extern "C" void kernel_launch(void* const* d_in, const int* in_sizes, int n_in,
                              void* d_out, int out_size, void* d_ws, size_t ws_size,
                              hipStream_t stream) {
    const float* x        = (const float*)d_in[0];
    const int*   day_idx  = (const int*)d_in[1];
    const float* day_w    = (const float*)d_in[2];
    const float* day_b    = (const float*)d_in[3];
    const float* w1       = (const float*)d_in[4];
    const float* b1       = (const float*)d_in[5];
    const float* w2       = (const float*)d_in[6];
    const float* b2       = (const float*)d_in[7];
    const float* ln_w     = (const float*)d_in[8];
    const float* ln_b     = (const float*)d_in[9];
    const float* m_in_w   = (const float*)d_in[10];
    const float* m_conv_w = (const float*)d_in[11];
    const float* m_conv_b = (const float*)d_in[12];
    const float* m_dt     = (const float*)d_in[13];
    const float* m_Alog   = (const float*)d_in[14];
    const float* m_D      = (const float*)d_in[15];
    const float* m_norm_w = (const float*)d_in[16];
    const float* m_out_w  = (const float*)d_in[17];
    const float* out_w    = (const float*)d_in[18];
    const float* out_b    = (const float*)d_in[19];

    float* ws = (float*)d_ws;
    // ---- prologue overlay (round-1 validated layout) ----
    short* hfb  = (short*)ws;                  // [4][2048][513] bf16    = 2,101,248 f (reserve 2,103,296)
    short* B1   = (short*)(ws + 2103296);      // [4096][7200] bf16      = 14,745,600 f -> ends 16,848,896
    short* h1b  = (short*)(ws + 16848896);     // [2036][4096] bf16      = 4,169,728 f  -> ends 21,018,624
    short* w2b  = (short*)(ws + 21018624);     // [512][4096] bf16       = 1,048,576 f  -> ends 22,067,200
    // ---- persistent ----
    float* hbuf = ws + 22067200;               // [2036][512]            = 1,042,432 f  -> ends 23,109,632
    short* hnb  = (short*)(ws + 23109632);     // [2036][512] bf16       = 521,216 f    -> ends 23,630,848
    // ---- loop overlay (reuses [0, 21,725,696); prologue bufs dead by then) ----
    float* zx2  = ws;                          // [2036][4384]           = 8,925,824 f
    float* xbcc = ws + 8925824;                // [2][2036][1152]        = 4,690,944 f
    short* ybf  = (short*)(ws + 8925824);      // [2036][2048] bf16 (overlays dead xbcc)
    float* ybuf = ws + 13616768;               // [2][2036][1024]        = 4,169,728 f
    float* Hbuf = ws + 17786496;               // [128][NC][64][64]      = 2,097,152 f
    float* Pcum = ws + 19883648;               // [128][509]             = 65,152 f
    float* dtb  = ws + 19948800;               // 65,152 f
    float* dab  = ws + 20013952;               // 65,152 f
    short* inwb = (short*)(ws + 20079104);     // [4384][512] bf16       = 1,122,304 f -> ends 21,201,408
    short* outwb= (short*)(ws + 21201408);     // [512][2048] bf16       = 524,288 f   -> ends 21,725,696

    day_gemm<<<dim3(8, 32, 4), 256, 0, stream>>>(x, day_idx, day_w, day_b, hfb);
    copy_xt<<<32, 256, 0, stream>>>(x, hfb);
    cvt_w1<<<14400, 256, 0, stream>>>(w1, B1);
    cvtk<<<2048, 256, 0, stream>>>(w2, w2b, (long)512 * PR);
    // patch-projection GEMM: single dispatch, A rows are bf16 patch windows in hfb
    // (contiguous, 8B-aligned -> AW=4), grid 512 blocks = 2/CU.
    bgemm<1, 0, 1, 0, 4><<<dim3(32, 16), 256, 0, stream>>>(
        hfb, B1, b1, h1b, M2, PR, KP1, TOUT, (long)TT * DIN, (long)4 * DIN, PR);
    // w2 GEMM: bias prefill + split-K atomic accumulate (K=4096 -> 4 slices)
    fillb<<<(M2 * DM + 255) / 256, 256, 0, stream>>>(hbuf, b2, M2 * DM, DM);
    bgemm<0, 0, 0, 1, 16><<<dim3(4, 16, 4), 256, 0, stream>>>(h1b, w2b, nullptr, hbuf,
                                                              M2, DM, PR, 1, (long)PR, 0L, DM);
    for (int i = 0; i < 5; i++) {
        ln_kernel<<<M2, 64, 0, stream>>>(hbuf, ln_w + i * DM, ln_b + i * DM, hnb);
        cvtk<<<2192, 256, 0, stream>>>(m_in_w + (size_t)2 * i * DINP * DM, inwb, (long)2 * DINP * DM);
        bgemm<0, 0, 0, 0, 16><<<dim3(35, 16), 256, 0, stream>>>(hnb, inwb, nullptr, zx2,
                                                                M2, ZLD, DM, 1, (long)DM, 0L, ZLD);
        conv_kernel<<<(2 * M2 * CONVD + 255) / 256, 256, 0, stream>>>(
            zx2, m_conv_w + (size_t)2 * i * CONVD * 4, m_conv_b + (size_t)2 * i * CONVD, xbcc);
        dt_kernel<<<(2 * M2 * Hh + 255) / 256, 256, 0, stream>>>(
            zx2, m_dt + 2 * i * Hh, m_Alog + 2 * i * Hh, dtb, dab);
        scan_local<<<dim3(Hh * NC, TB, 2), 64, 0, stream>>>(xbcc, dtb, dab, m_D + 2 * i * Hh,
                                                            ybuf, Hbuf, Pcum);
        scan_combine<<<128, 64, 0, stream>>>(Hbuf, Pcum);
        scan_fix<<<dim3(Hh * 4 * (NC - 1), TB, 2), 64, 0, stream>>>(xbcc, Hbuf, Pcum, ybuf);
        grms_kernel<<<dim3(M2, 2), 64, 0, stream>>>(ybuf, zx2, m_norm_w + (size_t)2 * i * DIc, ybf);
        cvt_outw<<<1024, 256, 0, stream>>>(m_out_w + (size_t)(2 * i) * DM * DIc,
                                           m_out_w + (size_t)(2 * i + 1) * DM * DIc, outwb);
        // merged fw+bw out-projection, split-K atomic accumulate onto residual (K=2048 -> 4 slices)
        bgemm<0, 0, 0, 1, 16><<<dim3(4, 16, 4), 256, 0, stream>>>(ybf, outwb, nullptr, hbuf,
                                                                  M2, DM, 2 * DIc, 1, (long)(2 * DIc), 0L, DM);
    }
    outk<<<M2, 64, 0, stream>>>(hbuf, out_w, out_b, (float*)d_out);
}